// Round 8
// baseline (362.954 us; speedup 1.0000x reference)
//
#include <hip/hip_runtime.h>
#include <math.h>

#define NPTS  16384
#define KNN   16
#define SEQV  8
#define BATCH 8
#define CAP   19     // 19.4 KB/block LDS -> 8 blocks/CU co-resident at nparts=32

__device__ __forceinline__ unsigned umin_(unsigned a, unsigned b) { return a < b ? a : b; }
__device__ __forceinline__ unsigned umax_(unsigned a, unsigned b) { return a > b ? a : b; }

// merge one key into sorted ascending keys[16]
__device__ __forceinline__ void merge_one(unsigned keys[KNN], unsigned kk) {
    if (kk < keys[KNN - 1]) {
#pragma unroll
        for (int u = 0; u < KNN; ++u) {
            unsigned lo = umin_(kk, keys[u]);
            kk = umax_(kk, keys[u]);
            keys[u] = lo;
        }
    }
}

// ---------------------------------------------------------------------------
// K1: sample scan. Grid (64, nparts) x 256. Thread (query i, partition p)
// cold-chains the first `samp` candidates of its partition -> part[p][i][16].
// Ping-pong prefetch. p==0 blocks also write pc4[i] = (x,y,z,|c|^2).
// Block (0,0) thread 0 zeroes accum (replaces the memset dispatch).
// key = (d2 bits & 0xFFFFC000) | j  (j < 2^14).
// ---------------------------------------------------------------------------
__global__ __launch_bounds__(256, 4) void sample_kernel(
    const float* __restrict__ pc, unsigned* __restrict__ part,
    float4* __restrict__ pc4, float* __restrict__ accum, int plen, int samp)
{
    const int i = blockIdx.x * 256 + threadIdx.x;
    const int p = blockIdx.y;

    if (p == 0 && i == 0) {
        accum[0] = 0.0f; accum[1] = 0.0f;
        ((unsigned*)accum)[2] = 0u; ((unsigned*)accum)[3] = 0u;
    }

    const float qx = pc[3 * i + 0];
    const float qy = pc[3 * i + 1];
    const float qz = pc[3 * i + 2];

    if (p == 0) {
        float q2 = fmaf(qx, qx, fmaf(qy, qy, qz * qz));
        pc4[i] = make_float4(qx, qy, qz, q2);
    }

    unsigned keys[KNN];
#pragma unroll
    for (int t = 0; t < KNN; ++t) keys[t] = 0xFFFFFFFFu;

    const int jbeg = p * plen;
    const float* cb = pc + 3 * (size_t)jbeg;

    float A[3 * BATCH], B[3 * BATCH];
#pragma unroll
    for (int u = 0; u < 3 * BATCH; ++u) A[u] = cb[u];

    auto process = [&](const float* C, int jbase) {
        unsigned kb[BATCH];
#pragma unroll
        for (int q = 0; q < BATCH; ++q) {
            float dx = qx - C[3 * q + 0];
            float dy = qy - C[3 * q + 1];
            float dz = qz - C[3 * q + 2];
            float d2 = fmaf(dx, dx, fmaf(dy, dy, dz * dz));
            kb[q] = (__float_as_uint(d2) & 0xFFFFC000u)
                  | (unsigned)(jbeg + jbase + q);
        }
#pragma unroll
        for (int q = 0; q < BATCH; ++q) merge_one(keys, kb[q]);
    };

#pragma unroll 1
    for (int jo = 0; jo < samp; jo += 2 * BATCH) {
#pragma unroll
        for (int u = 0; u < 3 * BATCH; ++u) B[u] = cb[3 * (jo + BATCH) + u];
        process(A, jo);
        if (jo + 2 * BATCH < samp) {
#pragma unroll
            for (int u = 0; u < 3 * BATCH; ++u) A[u] = cb[3 * (jo + 2 * BATCH) + u];
        }
        process(B, jo + BATCH);
    }

    unsigned* dst = part + ((size_t)p * NPTS + i) * KNN;
#pragma unroll
    for (int t = 0; t < KNN; ++t) dst[t] = keys[t];
}

// ---------------------------------------------------------------------------
// K2: tauf[i] = d16*(1+2e-4) + 1e-6 - |q_i|^2 from the merged 2048-sample
// (d16 >= global 16th; margin covers fma/truncation rounding -> exact filter).
// Also accumulates the weight sum into accum[1].
// ---------------------------------------------------------------------------
__global__ __launch_bounds__(256) void tau_kernel(
    const unsigned* __restrict__ part, const float4* __restrict__ pc4,
    const float* __restrict__ w, float* __restrict__ accum,
    float* __restrict__ taufArr, int nparts)
{
    const int i = blockIdx.x * 256 + threadIdx.x;

    unsigned keys[KNN];
#pragma unroll
    for (int t = 0; t < KNN; ++t) keys[t] = 0xFFFFFFFFu;

#pragma unroll 1
    for (int p = 0; p < nparts; ++p) {
        const unsigned* src = part + ((size_t)p * NPTS + i) * KNN;
#pragma unroll
        for (int t = 0; t < KNN; ++t) merge_one(keys, src[t]);
    }

    const float d16 = __uint_as_float(keys[KNN - 1] & 0xFFFFC000u);
    const float q2  = pc4[i].w;
    taufArr[i] = fmaf(d16, 1.0002f, 1e-6f) - q2;

    float wi = w[i];
#pragma unroll
    for (int off = 32; off > 0; off >>= 1) wi += __shfl_down(wi, off);
    if ((threadIdx.x & 63) == 0) atomicAdd(&accum[1], wi);
}

// ---------------------------------------------------------------------------
// K3: main filtered scan, ping-pong prefetched. Grid (64, nparts) x 256.
// Common path per candidate: 3 fma (dot) + 1 fma (d2') + cmp. Pack/append
// only in the exec-masked accept branch. 8 waves/SIMD (nparts=32) hide the
// candidate-load latency that R7's 4 waves could only half-hide.
// ---------------------------------------------------------------------------
__global__ __launch_bounds__(256, 8) void knn_main_kernel(
    const float4* __restrict__ pc4, const float* __restrict__ taufArr,
    unsigned* __restrict__ part, int plen)
{
    __shared__ unsigned sbuf[256 * CAP];
    unsigned* buf = &sbuf[threadIdx.x * CAP];

    const int i = blockIdx.x * 256 + threadIdx.x;
    const int p = blockIdx.y;

    const float4 qv = pc4[i];
    const float qx = qv.x, qy = qv.y, qz = qv.z, q2 = qv.w;

    float tauf = taufArr[i];

    unsigned keys[KNN];
#pragma unroll
    for (int t = 0; t < KNN; ++t) keys[t] = 0xFFFFFFFFu;
    int cnt = 0;

    const int jbeg = p * plen;
    const float4* cb = pc4 + jbeg;

    float4 A[BATCH], B[BATCH];
#pragma unroll
    for (int q = 0; q < BATCH; ++q) A[q] = cb[q];

    auto process = [&](const float4* C, int jbase) {
#pragma unroll
        for (int q = 0; q < BATCH; ++q) {
            const float4 c = C[q];
            float dot = fmaf(c.x, qx, fmaf(c.y, qy, c.z * qz));
            float d2p = fmaf(-2.0f, dot, c.w);     // d2 - q2 (monotone in d2)
            if (d2p <= tauf) {                     // exec-masked accept
                float d2 = fmaxf(d2p + q2, 0.0f);  // clamp: self ~ -1e-7
                unsigned key = (__float_as_uint(d2) & 0xFFFFC000u)
                             | (unsigned)(jbeg + jbase + q);
                buf[cnt] = key;
                ++cnt;
            }
        }
        // headroom: enter batch with cnt <= CAP-BATCH-1 = 10 -> max idx 17
        if (cnt >= CAP - BATCH) {
#pragma unroll 1
            for (int t = 0; t < cnt; ++t) merge_one(keys, buf[t]);
            cnt = 0;
            float d16n = __uint_as_float(keys[KNN - 1] & 0xFFFFC000u);
            tauf = fminf(tauf, fmaf(d16n, 1.0002f, 1e-6f) - q2);  // NaN-safe
        }
    };

#pragma unroll 1
    for (int jo = 0; jo < plen; jo += 2 * BATCH) {
#pragma unroll
        for (int q = 0; q < BATCH; ++q) B[q] = cb[jo + BATCH + q];
        process(A, jo);
        if (jo + 2 * BATCH < plen) {
#pragma unroll
            for (int q = 0; q < BATCH; ++q) A[q] = cb[jo + 2 * BATCH + q];
        }
        process(B, jo + BATCH);
    }

#pragma unroll 1
    for (int t = 0; t < cnt; ++t) merge_one(keys, buf[t]);

    unsigned* dst = part + ((size_t)p * NPTS + i) * KNN;
#pragma unroll
    for (int t = 0; t < KNN; ++t) dst[t] = keys[t];
}

// ---------------------------------------------------------------------------
// K4: merge + radius + loss + finalize. Grid (64,4) x 512.
// Block (x,sg): queries [256x,256x+256), seqs {2sg, 2sg+1}; tid = q + 256*e.
// e==0 half merges the nparts lists -> radius-filtered ids in LDS; all gather.
// accum[0]=loss, accum[1]=wsum, accum[2]=ticket (zeroed by sample_kernel).
// ---------------------------------------------------------------------------
__global__ __launch_bounds__(512) void loss_kernel(
    const float* __restrict__ flow, const float* __restrict__ w,
    const unsigned* __restrict__ part, float* __restrict__ accum,
    float* __restrict__ out, int nparts)
{
    __shared__ int   sIds[256 * 17];   // stride 17 -> conflict-free
    __shared__ float sred[8];

    const int tid = threadIdx.x;
    const int q   = tid & 255;
    const int e   = tid >> 8;          // 0..1
    const int i   = blockIdx.x * 256 + q;
    const int sg  = blockIdx.y;        // 0..3

    if (e == 0) {
        unsigned keys[KNN];
#pragma unroll
        for (int t = 0; t < KNN; ++t) keys[t] = 0xFFFFFFFFu;
#pragma unroll 1
        for (int p = 0; p < nparts; ++p) {
            const unsigned* src = part + ((size_t)p * NPTS + i) * KNN;
#pragma unroll
            for (int t = 0; t < KNN; ++t) merge_one(keys, src[t]);
        }
        const int id0 = (int)(keys[0] & 0x3FFFu);   // nearest (self)
#pragma unroll
        for (int t = 0; t < KNN; ++t) {
            float d2t = __uint_as_float(keys[t] & 0xFFFFC000u);
            int   j   = (int)(keys[t] & 0x3FFFu);
            sIds[q * 17 + t] = (d2t > 1.0f) ? id0 : j;
        }
    }
    __syncthreads();

    const int s = sg * 2 + e;
    const float* fs = flow + (size_t)s * NPTS * 3;
    const float fx = fs[3 * i + 0];
    const float fy = fs[3 * i + 1];
    const float fz = fs[3 * i + 2];

    float sum = 0.0f;
#pragma unroll
    for (int t = 0; t < KNN; ++t) {
        int j = sIds[q * 17 + t];
        float dx = fx - fs[3 * j + 0];
        float dy = fy - fs[3 * j + 1];
        float dz = fz - fs[3 * j + 2];
        float sq = fmaf(dx, dx, fmaf(dy, dy, dz * dz));
        sum += (sq > 0.0f) ? sqrtf(sq) : 0.0f;
    }

    float contrib = w[i] * sum;
#pragma unroll
    for (int off = 32; off > 0; off >>= 1) contrib += __shfl_down(contrib, off);
    if ((tid & 63) == 0) sred[tid >> 6] = contrib;
    __syncthreads();

    if (tid == 0) {
        float c = 0.0f;
#pragma unroll
        for (int t = 0; t < 8; ++t) c += sred[t];
        atomicAdd(&accum[0], c);
        __threadfence();
        unsigned ticket = atomicAdd((unsigned*)&accum[2], 1u);
        if (ticket == 64 * 4 - 1) {     // last block finalizes
            float a  = atomicAdd(&accum[0], 0.0f);   // coherent read
            float ws = atomicAdd(&accum[1], 0.0f);
            float v  = a / (float)(KNN * SEQV);
            out[0] = (ws > 0.0f) ? (v / ws) : v;
        }
    }
}

extern "C" void kernel_launch(void* const* d_in, const int* in_sizes, int n_in,
                              void* d_out, int out_size, void* d_ws, size_t ws_size,
                              hipStream_t stream)
{
    const float* pc   = (const float*)d_in[0];   // (1, N, 3)
    const float* flow = (const float*)d_in[1];   // (SEQ, N, 3)
    const float* wts  = (const float*)d_in[2];   // (N,)
    float* out = (float*)d_out;

    // layout: accum(256 B) | tauf(64 KB) | pc4(256 KB) | part(nparts*1 MB)
    float*    accum = (float*)d_ws;
    float*    tauf  = (float*)((char*)d_ws + 256);
    float4*   pc4   = (float4*)((char*)d_ws + 256 + NPTS * 4);
    unsigned* part  = (unsigned*)((char*)d_ws + 256 + NPTS * 4 + NPTS * 16);

    const size_t fixed  = 256 + NPTS * 4 + (size_t)NPTS * 16;
    const size_t need32 = fixed + (size_t)32 * NPTS * KNN * 4;
    const int nparts = (ws_size >= need32) ? 32 : 16;   // 8 vs 4 waves/SIMD
    const int plen   = NPTS / nparts;
    const int samp   = 2048 / nparts;   // global sample stays 2048

    sample_kernel<<<dim3(NPTS / 256, nparts), 256, 0, stream>>>(pc, part, pc4,
                                                                accum, plen, samp);
    tau_kernel<<<NPTS / 256, 256, 0, stream>>>(part, pc4, wts, accum, tauf, nparts);
    knn_main_kernel<<<dim3(NPTS / 256, nparts), 256, 0, stream>>>(pc4, tauf, part, plen);
    loss_kernel<<<dim3(NPTS / 256, 4), 512, 0, stream>>>(flow, wts, part, accum,
                                                         out, nparts);
}

// Round 9
// 232.396 us; speedup vs baseline: 1.5618x; 1.5618x over previous
//
#include <hip/hip_runtime.h>
#include <math.h>

#define NPTS  16384
#define KNN   16
#define SEQV  8
#define NPART 16
#define PLEN  (NPTS / NPART)   // 1024
#define SAMP  128              // global sample = 2048
#define BATCH 8
#define CAP   25               // odd stride -> spread banks; 25.6 KB/block

__device__ __forceinline__ unsigned umin_(unsigned a, unsigned b) { return a < b ? a : b; }
__device__ __forceinline__ unsigned umax_(unsigned a, unsigned b) { return a > b ? a : b; }

// merge one key into sorted ascending keys[16]
__device__ __forceinline__ void merge_one(unsigned keys[KNN], unsigned kk) {
    if (kk < keys[KNN - 1]) {
#pragma unroll
        for (int u = 0; u < KNN; ++u) {
            unsigned lo = umin_(kk, keys[u]);
            kk = umax_(kk, keys[u]);
            keys[u] = lo;
        }
    }
}

// ---------------------------------------------------------------------------
// K1: sample scan. Grid (64, NPART) x 256. Thread (query i, partition p)
// cold-chains the first SAMP candidates of partition p -> part[i][p][16]
// (transposed layout: each query's lists are one contiguous 1 KB stream).
// Ping-pong prefetch. p==0 blocks write pc4[i]; block (0,0) zeroes accum.
// key = (d2 bits & 0xFFFFC000) | j  (j < 2^14).
// ---------------------------------------------------------------------------
__global__ __launch_bounds__(256) void sample_kernel(
    const float* __restrict__ pc, unsigned* __restrict__ part,
    float4* __restrict__ pc4, float* __restrict__ accum)
{
    const int i = blockIdx.x * 256 + threadIdx.x;
    const int p = blockIdx.y;

    if (p == 0 && i == 0) {
        accum[0] = 0.0f; accum[1] = 0.0f;
        ((unsigned*)accum)[2] = 0u; ((unsigned*)accum)[3] = 0u;
    }

    const float qx = pc[3 * i + 0];
    const float qy = pc[3 * i + 1];
    const float qz = pc[3 * i + 2];

    if (p == 0) {
        float q2 = fmaf(qx, qx, fmaf(qy, qy, qz * qz));
        pc4[i] = make_float4(qx, qy, qz, q2);
    }

    unsigned keys[KNN];
#pragma unroll
    for (int t = 0; t < KNN; ++t) keys[t] = 0xFFFFFFFFu;

    const int jbeg = p * PLEN;
    const float* cb = pc + 3 * (size_t)jbeg;

    float A[3 * BATCH], B[3 * BATCH];
#pragma unroll
    for (int u = 0; u < 3 * BATCH; ++u) A[u] = cb[u];

    auto process = [&](const float* C, int jbase) {
        unsigned kb[BATCH];
#pragma unroll
        for (int q = 0; q < BATCH; ++q) {
            float dx = qx - C[3 * q + 0];
            float dy = qy - C[3 * q + 1];
            float dz = qz - C[3 * q + 2];
            float d2 = fmaf(dx, dx, fmaf(dy, dy, dz * dz));
            kb[q] = (__float_as_uint(d2) & 0xFFFFC000u)
                  | (unsigned)(jbeg + jbase + q);
        }
#pragma unroll
        for (int q = 0; q < BATCH; ++q) merge_one(keys, kb[q]);
    };

#pragma unroll 1
    for (int jo = 0; jo < SAMP; jo += 2 * BATCH) {
#pragma unroll
        for (int u = 0; u < 3 * BATCH; ++u) B[u] = cb[3 * (jo + BATCH) + u];
        process(A, jo);
        if (jo + 2 * BATCH < SAMP) {
#pragma unroll
            for (int u = 0; u < 3 * BATCH; ++u) A[u] = cb[3 * (jo + 2 * BATCH) + u];
        }
        process(B, jo + BATCH);
    }

    unsigned* dst = part + ((size_t)i * NPART + p) * KNN;
#pragma unroll
    for (int t = 0; t < KNN; ++t) dst[t] = keys[t];
}

// ---------------------------------------------------------------------------
// K2: tauf[i] = d16*(1+2e-4) + 1e-6 - |q_i|^2 from the merged 2048-sample.
// Ping-pong prefetch over the contiguous 16 lists. Also weight sum.
// ---------------------------------------------------------------------------
__global__ __launch_bounds__(256) void tau_kernel(
    const unsigned* __restrict__ part, const float4* __restrict__ pc4,
    const float* __restrict__ w, float* __restrict__ accum,
    float* __restrict__ taufArr)
{
    const int i = blockIdx.x * 256 + threadIdx.x;
    const uint4* lists = (const uint4*)(part + (size_t)i * NPART * KNN);

    unsigned keys[KNN];
#pragma unroll
    for (int t = 0; t < KNN; ++t) keys[t] = 0xFFFFFFFFu;

    uint4 A4[4], B4[4];
#pragma unroll
    for (int u = 0; u < 4; ++u) A4[u] = lists[u];

    auto merge_list = [&](const uint4* L) {
        const unsigned* lk = (const unsigned*)L;
#pragma unroll
        for (int t = 0; t < KNN; ++t) merge_one(keys, lk[t]);
    };

#pragma unroll 1
    for (int p = 0; p < NPART; p += 2) {
#pragma unroll
        for (int u = 0; u < 4; ++u) B4[u] = lists[4 * (p + 1) + u];
        merge_list(A4);
        if (p + 2 < NPART) {
#pragma unroll
            for (int u = 0; u < 4; ++u) A4[u] = lists[4 * (p + 2) + u];
        }
        merge_list(B4);
    }

    const float d16 = __uint_as_float(keys[KNN - 1] & 0xFFFFC000u);
    const float q2  = pc4[i].w;
    taufArr[i] = fmaf(d16, 1.0002f, 1e-6f) - q2;

    float wi = w[i];
#pragma unroll
    for (int off = 32; off > 0; off >>= 1) wi += __shfl_down(wi, off);
    if ((threadIdx.x & 63) == 0) atomicAdd(&accum[1], wi);
}

// ---------------------------------------------------------------------------
// K3: main filtered scan, ping-pong prefetched (R7 structure, transposed out).
// Grid (64, NPART) x 256. Common path: 3 fma (dot) + 1 fma (d2') + cmp.
// ---------------------------------------------------------------------------
__global__ __launch_bounds__(256, 4) void knn_main_kernel(
    const float4* __restrict__ pc4, const float* __restrict__ taufArr,
    unsigned* __restrict__ part)
{
    __shared__ unsigned sbuf[256 * CAP];
    unsigned* buf = &sbuf[threadIdx.x * CAP];

    const int i = blockIdx.x * 256 + threadIdx.x;
    const int p = blockIdx.y;

    const float4 qv = pc4[i];
    const float qx = qv.x, qy = qv.y, qz = qv.z, q2 = qv.w;

    float tauf = taufArr[i];

    unsigned keys[KNN];
#pragma unroll
    for (int t = 0; t < KNN; ++t) keys[t] = 0xFFFFFFFFu;
    int cnt = 0;

    const int jbeg = p * PLEN;
    const float4* cb = pc4 + jbeg;

    float4 A[BATCH], B[BATCH];
#pragma unroll
    for (int q = 0; q < BATCH; ++q) A[q] = cb[q];

    auto process = [&](const float4* C, int jbase) {
#pragma unroll
        for (int q = 0; q < BATCH; ++q) {
            const float4 c = C[q];
            float dot = fmaf(c.x, qx, fmaf(c.y, qy, c.z * qz));
            float d2p = fmaf(-2.0f, dot, c.w);     // d2 - q2 (monotone in d2)
            if (d2p <= tauf) {                     // exec-masked accept
                float d2 = fmaxf(d2p + q2, 0.0f);  // clamp: self ~ -1e-7
                unsigned key = (__float_as_uint(d2) & 0xFFFFC000u)
                             | (unsigned)(jbeg + jbase + q);
                buf[cnt] = key;
                ++cnt;
            }
        }
        // headroom: enter batch with cnt <= CAP-BATCH-1 = 16 -> max idx 23
        if (cnt >= CAP - BATCH) {
#pragma unroll 1
            for (int t = 0; t < cnt; ++t) merge_one(keys, buf[t]);
            cnt = 0;
            float d16n = __uint_as_float(keys[KNN - 1] & 0xFFFFC000u);
            tauf = fminf(tauf, fmaf(d16n, 1.0002f, 1e-6f) - q2);  // NaN-safe
        }
    };

#pragma unroll 1
    for (int jo = 0; jo < PLEN; jo += 2 * BATCH) {
#pragma unroll
        for (int q = 0; q < BATCH; ++q) B[q] = cb[jo + BATCH + q];
        process(A, jo);
        if (jo + 2 * BATCH < PLEN) {
#pragma unroll
            for (int q = 0; q < BATCH; ++q) A[q] = cb[jo + 2 * BATCH + q];
        }
        process(B, jo + BATCH);
    }

#pragma unroll 1
    for (int t = 0; t < cnt; ++t) merge_one(keys, buf[t]);

    unsigned* dst = part + ((size_t)i * NPART + p) * KNN;
#pragma unroll
    for (int t = 0; t < KNN; ++t) dst[t] = keys[t];
}

// ---------------------------------------------------------------------------
// K4: merge + radius + loss + finalize. Grid (64,4) x 512.
// Split-merge: e==0 merges lists 0..7, e==1 merges 8..15 (ping-pong
// prefetched), halves meet in LDS, e==0 cross-merges + radius -> ids in LDS.
// Then all threads gather seq s = 2*sg + e.
// accum[0]=loss, accum[1]=wsum, accum[2]=ticket (zeroed by sample_kernel).
// ---------------------------------------------------------------------------
__global__ __launch_bounds__(512) void loss_kernel(
    const float* __restrict__ flow, const float* __restrict__ w,
    const unsigned* __restrict__ part, float* __restrict__ accum,
    float* __restrict__ out)
{
    __shared__ unsigned sKeys[256 * 34];   // q*34 + e*17 + t ; stride 34 -> 2-way (free)
    __shared__ float sred[8];

    const int tid = threadIdx.x;
    const int q   = tid & 255;
    const int e   = tid >> 8;          // 0..1
    const int i   = blockIdx.x * 256 + q;
    const int sg  = blockIdx.y;        // 0..3

    // ---- half-merge: 8 lists each, ping-pong prefetch ----
    const uint4* lists = (const uint4*)(part + ((size_t)i * NPART + e * 8) * KNN);

    unsigned keys[KNN];
#pragma unroll
    for (int t = 0; t < KNN; ++t) keys[t] = 0xFFFFFFFFu;

    uint4 A4[4], B4[4];
#pragma unroll
    for (int u = 0; u < 4; ++u) A4[u] = lists[u];

    auto merge_list = [&](const uint4* L) {
        const unsigned* lk = (const unsigned*)L;
#pragma unroll
        for (int t = 0; t < KNN; ++t) merge_one(keys, lk[t]);
    };

#pragma unroll 1
    for (int p = 0; p < 8; p += 2) {
#pragma unroll
        for (int u = 0; u < 4; ++u) B4[u] = lists[4 * (p + 1) + u];
        merge_list(A4);
        if (p + 2 < 8) {
#pragma unroll
            for (int u = 0; u < 4; ++u) A4[u] = lists[4 * (p + 2) + u];
        }
        merge_list(B4);
    }

#pragma unroll
    for (int t = 0; t < KNN; ++t) sKeys[q * 34 + e * 17 + t] = keys[t];
    __syncthreads();

    if (e == 0) {
        // cross-merge other half + radius filter -> ids overwrite sKeys[q*34+t]
#pragma unroll
        for (int t = 0; t < KNN; ++t) merge_one(keys, sKeys[q * 34 + 17 + t]);
        const int id0 = (int)(keys[0] & 0x3FFFu);   // nearest (self)
#pragma unroll
        for (int t = 0; t < KNN; ++t) {
            float d2t = __uint_as_float(keys[t] & 0xFFFFC000u);
            int   j   = (int)(keys[t] & 0x3FFFu);
            sKeys[q * 34 + t] = (unsigned)((d2t > 1.0f) ? id0 : j);
        }
    }
    __syncthreads();

    const int s = sg * 2 + e;
    const float* fs = flow + (size_t)s * NPTS * 3;
    const float fx = fs[3 * i + 0];
    const float fy = fs[3 * i + 1];
    const float fz = fs[3 * i + 2];

    float sum = 0.0f;
#pragma unroll
    for (int t = 0; t < KNN; ++t) {
        int j = (int)sKeys[q * 34 + t];
        float dx = fx - fs[3 * j + 0];
        float dy = fy - fs[3 * j + 1];
        float dz = fz - fs[3 * j + 2];
        float sq = fmaf(dx, dx, fmaf(dy, dy, dz * dz));
        sum += (sq > 0.0f) ? sqrtf(sq) : 0.0f;
    }

    float contrib = w[i] * sum;
#pragma unroll
    for (int off = 32; off > 0; off >>= 1) contrib += __shfl_down(contrib, off);
    if ((tid & 63) == 0) sred[tid >> 6] = contrib;
    __syncthreads();

    if (tid == 0) {
        float c = 0.0f;
#pragma unroll
        for (int t = 0; t < 8; ++t) c += sred[t];
        atomicAdd(&accum[0], c);
        __threadfence();
        unsigned ticket = atomicAdd((unsigned*)&accum[2], 1u);
        if (ticket == 64 * 4 - 1) {     // last block finalizes
            float a  = atomicAdd(&accum[0], 0.0f);   // coherent read
            float ws = atomicAdd(&accum[1], 0.0f);
            float v  = a / (float)(KNN * SEQV);
            out[0] = (ws > 0.0f) ? (v / ws) : v;
        }
    }
}

extern "C" void kernel_launch(void* const* d_in, const int* in_sizes, int n_in,
                              void* d_out, int out_size, void* d_ws, size_t ws_size,
                              hipStream_t stream)
{
    const float* pc   = (const float*)d_in[0];   // (1, N, 3)
    const float* flow = (const float*)d_in[1];   // (SEQ, N, 3)
    const float* wts  = (const float*)d_in[2];   // (N,)
    float* out = (float*)d_out;

    // layout: accum(256 B) | tauf(64 KB) | pc4(256 KB) | part(16.8 MB)
    float*    accum = (float*)d_ws;
    float*    tauf  = (float*)((char*)d_ws + 256);
    float4*   pc4   = (float4*)((char*)d_ws + 256 + NPTS * 4);
    unsigned* part  = (unsigned*)((char*)d_ws + 256 + NPTS * 4 + NPTS * 16);

    sample_kernel<<<dim3(NPTS / 256, NPART), 256, 0, stream>>>(pc, part, pc4, accum);
    tau_kernel<<<NPTS / 256, 256, 0, stream>>>(part, pc4, wts, accum, tauf);
    knn_main_kernel<<<dim3(NPTS / 256, NPART), 256, 0, stream>>>(pc4, tauf, part);
    loss_kernel<<<dim3(NPTS / 256, 4), 512, 0, stream>>>(flow, wts, part, accum, out);
}